// Round 5
// baseline (227.053 us; speedup 1.0000x reference)
//
#include <hip/hip_runtime.h>

typedef __attribute__((ext_vector_type(8))) short s16x8;
typedef __attribute__((ext_vector_type(4))) float f32x4;

#define BB   512
#define LL   2048
#define DD   128
#define HH   128
#define SUB  64               // leaves per k1 block (32 KB LDS -> 5 blocks/CU)
#define NSUB (LL / SUB)       // 32 subtrees per sample
#define K1ROWS 4              // rows k1 leaves per subtree (5 comp levels)
#define K2ROWS (NSUB * K1ROWS)  // 128 rows per sample into k2 (16 MB ws)

// f32 -> bf16 bits, RNE
__device__ __forceinline__ short f2bf(float x) {
  unsigned u = __builtin_bit_cast(unsigned, x);
  u += 0x7fffu + ((u >> 16) & 1u);
  return (short)(u >> 16);
}
// packed f32x2 -> bf16x2 (gfx950 v_cvt_pk_bf16_f32, RNE)
__device__ __forceinline__ unsigned pk_bf16(float a, float b) {
  unsigned r;
  asm("v_cvt_pk_bf16_f32 %0, %1, %2" : "=v"(r) : "v"(a), "v"(b));
  return r;
}
// tanh via exp; valid-row preacts are norm-bounded. Garbage (stale-pad) rows
// may produce NaN — contained: NaN only reaches write-masked D rows.
__device__ __forceinline__ float tanh_fast(float x) {
  float e2 = __expf(2.f * x);
  return (e2 - 1.f) * __builtin_amdgcn_rcpf(e2 + 1.f);
}

// LDS byte address for [row][inner(bytes)] in a [*][256B] bf16 tile; XOR
// swizzle breaks the 256B-row-stride bank alignment for strided ds_read_b128.
__device__ __forceinline__ int swz(int row, int inner) {
  return row * 256 + (inner ^ (((row >> 1) & 7) << 4));
}

// ---- prep: W_in^T, W_comp^T as bf16 ----
__global__ __launch_bounds__(256) void k_prep(
    const float* __restrict__ Win, const float* __restrict__ Wcomp,
    short* __restrict__ WiT, short* __restrict__ WcT) {
  const int i0 = blockIdx.x * 256 + threadIdx.x;
  const int stride = gridDim.x * 256;
  for (int idx = i0; idx < 128 * 128; idx += stride) {
    int n = idx >> 7, k = idx & 127;
    WiT[idx] = f2bf(Win[k * 128 + n]);     // WiT[n][k]
  }
  for (int idx = i0; idx < 128 * 256; idx += stride) {
    int n = idx >> 8, k = idx & 255;
    WcT[idx] = f2bf(Wcomp[k * 128 + n]);   // WcT[n][k]
  }
}

// One 16-row tree M-tile: A row i = concat(src[2*(mt_in*16+i)], src[...+1]),
// K=256 against wfc.
__device__ __forceinline__ void tree_mm(const short* src, int mt_in,
                                        const s16x8 (&wfc)[8][2], int lm,
                                        int lh, f32x4& c0, f32x4& c1) {
  s16x8 a[8];
#pragma unroll
  for (int kt = 0; kt < 8; ++kt) {
    int k = kt * 32 + lh * 8;
    int rowbuf = 2 * (mt_in * 16 + lm) + (k >> 7);
    a[kt] = *(const s16x8*)((const char*)src + swz(rowbuf, (k & 127) * 2));
  }
  c0 = (f32x4){0.f, 0.f, 0.f, 0.f};
  c1 = (f32x4){0.f, 0.f, 0.f, 0.f};
#pragma unroll
  for (int kt = 0; kt < 8; ++kt) {
    c0 = __builtin_amdgcn_mfma_f32_16x16x32_bf16(a[kt], wfc[kt][0], c0, 0, 0, 0);
    c1 = __builtin_amdgcn_mfma_f32_16x16x32_bf16(a[kt], wfc[kt][1], c1, 0, 0, 0);
  }
}

__global__ __launch_bounds__(256, 5) void k_subtree(
    const int* __restrict__ ids, const float* __restrict__ emb,
    const short* __restrict__ WiT, const float* __restrict__ bin,
    const short* __restrict__ WcT, const float* __restrict__ bcomp,
    short* __restrict__ wsbf) {
  __shared__ __align__(16) short ldsE[64 * 128];  // 16 KB (E / tree ping)
  __shared__ __align__(16) short ldsB[64 * 128];  // 16 KB (h0 out / tree pong)
  const int blk = blockIdx.x, tid = threadIdx.x;
  const int wave = tid >> 6, lane = tid & 63;
  const int lh = lane >> 4, lm = lane & 15;
  const int n0 = wave * 32;
  const int col0 = n0 + 2 * lm;  // lane owns cols col0, col0+1

  // leaf ids (one row per thread-role per iter)
  int idv[8];
#pragma unroll
  for (int it = 0; it < 8; ++it)
    idv[it] = ids[(long)blk * SUB + it * 8 + (tid >> 5)];

  // W_in fragments (live only through h0); K=128 -> kt in [0,4)
  s16x8 wfin[4][2];
#pragma unroll
  for (int kt = 0; kt < 4; ++kt)
#pragma unroll
    for (int nt = 0; nt < 2; ++nt)
      wfin[kt][nt] = *(const s16x8*)(WiT + (col0 + nt) * 128 + kt * 32 + lh * 8);
  const float2 biv = *(const float2*)(bin + col0);
  const float2 bcv = *(const float2*)(bcomp + col0);

  // gather all 64 rows -> ldsE (single phase)
#pragma unroll
  for (int it = 0; it < 8; ++it) {
    int r = it * 8 + (tid >> 5);
    const float4 v = ((const float4*)(emb + (long)idv[it] * DD))[tid & 31];
    uint2 pv;
    pv.x = pk_bf16(v.x, v.y);
    pv.y = pk_bf16(v.z, v.w);
    *(uint2*)((char*)ldsE + swz(r, (tid & 31) * 8)) = pv;
  }
  __syncthreads();

  // h0 = E @ W_in + b_in: 4 m-tiles -> ldsB rows 0-63 (no tanh at level 0)
#pragma unroll 1
  for (int mt = 0; mt < 4; ++mt) {
    s16x8 a[4];
#pragma unroll
    for (int kt = 0; kt < 4; ++kt)
      a[kt] = *(const s16x8*)((const char*)ldsE +
                              swz(mt * 16 + lm, kt * 64 + lh * 16));
    f32x4 c0 = {0.f, 0.f, 0.f, 0.f}, c1 = {0.f, 0.f, 0.f, 0.f};
#pragma unroll
    for (int kt = 0; kt < 4; ++kt) {
      c0 = __builtin_amdgcn_mfma_f32_16x16x32_bf16(a[kt], wfin[kt][0], c0, 0, 0, 0);
      c1 = __builtin_amdgcn_mfma_f32_16x16x32_bf16(a[kt], wfin[kt][1], c1, 0, 0, 0);
    }
#pragma unroll
    for (int r = 0; r < 4; ++r) {
      int row = mt * 16 + lh * 4 + r;
      *(unsigned*)((char*)ldsB + swz(row, col0 * 2)) =
          pk_bf16(c0[r] + biv.x, c1[r] + biv.y);
    }
  }

  // W_comp fragments (wfin now dead; loads overlap h0 tail)
  s16x8 wfc[8][2];
#pragma unroll
  for (int kt = 0; kt < 8; ++kt)
#pragma unroll
    for (int nt = 0; nt < 2; ++nt)
      wfc[kt][nt] = *(const s16x8*)(WcT + (col0 + nt) * 256 + kt * 32 + lh * 8);
  __syncthreads();

  // lev0: ldsB(64 rows) -> ldsE(32 rows, all valid)
#pragma unroll 1
  for (int mt = 0; mt < 2; ++mt) {
    f32x4 c0, c1;
    tree_mm(ldsB, mt, wfc, lm, lh, c0, c1);
#pragma unroll
    for (int r = 0; r < 4; ++r) {
      int row = mt * 16 + lh * 4 + r;
      *(unsigned*)((char*)ldsE + swz(row, col0 * 2)) =
          pk_bf16(tanh_fast(c0[r] + bcv.x), tanh_fast(c1[r] + bcv.y));
    }
  }
  __syncthreads();

  // lev1: ldsE(32) -> ldsB(16 rows, all valid)
  {
    f32x4 c0, c1;
    tree_mm(ldsE, 0, wfc, lm, lh, c0, c1);
#pragma unroll
    for (int r = 0; r < 4; ++r) {
      int row = lh * 4 + r;
      *(unsigned*)((char*)ldsB + swz(row, col0 * 2)) =
          pk_bf16(tanh_fast(c0[r] + bcv.x), tanh_fast(c1[r] + bcv.y));
    }
  }
  __syncthreads();

  // lev2: ldsB(16 valid; 16-31 stale h0, finite) -> ldsE(rows 0-7 valid,
  // 8-15 garbage-finite-or-NaN; NaN contained to masked rows downstream)
  {
    f32x4 c0, c1;
    tree_mm(ldsB, 0, wfc, lm, lh, c0, c1);
#pragma unroll
    for (int r = 0; r < 4; ++r) {
      int row = lh * 4 + r;
      *(unsigned*)((char*)ldsE + swz(row, col0 * 2)) =
          pk_bf16(tanh_fast(c0[r] + bcv.x), tanh_fast(c1[r] + bcv.y));
    }
  }
  __syncthreads();

  // lev3: ldsE(8 valid rows; 8-15 garbage, 16-31 stale lev0) -> global, 4 rows
  // D rows 0-3 use A pair-rows 0-7 (valid only); garbage reaches rows >=4.
  {
    f32x4 c0, c1;
    tree_mm(ldsE, 0, wfc, lm, lh, c0, c1);
#pragma unroll
    for (int r = 0; r < 4; ++r) {
      int row = lh * 4 + r;
      if (row < K1ROWS)
        *(unsigned*)(wsbf + ((long)blk * K1ROWS + row) * HH + col0) =
            pk_bf16(tanh_fast(c0[r] + bcv.x), tanh_fast(c1[r] + bcv.y));
    }
  }
}

// ---- k2: per-sample 128 rows -> root -> classifier (MFMA) ----
__global__ __launch_bounds__(256, 2) void k_tree2(
    const short* __restrict__ wsbf, const short* __restrict__ WcT,
    const float* __restrict__ bcomp, const float* __restrict__ Wcls,
    const float* __restrict__ bcls, float* __restrict__ out) {
  __shared__ __align__(16) short srcL[128 * 128];  // 32 KB
  __shared__ __align__(16) short dstS[64 * 128];   // 16 KB
  __shared__ float rootL[128];
  const int b = blockIdx.x, tid = threadIdx.x;
  const int wave = tid >> 6, lane = tid & 63;
  const int lh = lane >> 4, lm = lane & 15;
  const int n0 = wave * 32;
  const int col0 = n0 + 2 * lm;

  s16x8 wfc[8][2];
#pragma unroll
  for (int kt = 0; kt < 8; ++kt)
#pragma unroll
    for (int nt = 0; nt < 2; ++nt)
      wfc[kt][nt] = *(const s16x8*)(WcT + (col0 + nt) * 256 + kt * 32 + lh * 8);
  const float2 bcv = *(const float2*)(bcomp + col0);

  // load 128 rows of bf16 (16 B per lane, coalesced) -> srcL swizzled
#pragma unroll
  for (int it = 0; it < 8; ++it) {
    int row = it * 16 + (tid >> 4);
    s16x8 v = *(const s16x8*)(wsbf + ((long)b * K2ROWS + row) * HH + (tid & 15) * 8);
    *(s16x8*)((char*)srcL + swz(row, (tid & 15) * 16)) = v;
  }
  __syncthreads();

  const short* src = srcL;
  short* dst = dstS;
  // levels: 128->64->32->16->8->4->2->1 ; mtiles 4,2,1,1,1,1,1
  const int mtiles[7] = {4, 2, 1, 1, 1, 1, 1};
  const int rlim[7] = {64, 32, 16, 8, 4, 2, 1};
#pragma unroll 1
  for (int lev = 0; lev < 7; ++lev) {
    int nmt = mtiles[lev], rl = rlim[lev];
#pragma unroll 1
    for (int mt = 0; mt < nmt; ++mt) {
      f32x4 c0, c1;
      tree_mm(src, mt, wfc, lm, lh, c0, c1);
      if (lev == 6) {
        if (lh == 0) {
          rootL[col0] = tanh_fast(c0[0] + bcv.x);
          rootL[col0 + 1] = tanh_fast(c1[0] + bcv.y);
        }
      } else {
#pragma unroll
        for (int r = 0; r < 4; ++r) {
          int row = mt * 16 + lh * 4 + r;
          if (row < rl)
            *(unsigned*)((char*)dst + swz(row, col0 * 2)) =
                pk_bf16(tanh_fast(c0[r] + bcv.x), tanh_fast(c1[r] + bcv.y));
        }
      }
    }
    __syncthreads();
    const short* t = src;
    src = dst;
    dst = (short*)t;
  }

  // classifier: wave 0; lane -> (class = lane&1, k-chunk = lane>>1)
  if (wave == 0) {
    int c = lane & 1, kb = lane >> 1;
    float p = 0.f;
#pragma unroll
    for (int j = 0; j < 4; ++j) {
      int k = kb + 32 * j;
      p += rootL[k] * Wcls[k * 2 + c];
    }
#pragma unroll
    for (int m = 2; m <= 32; m <<= 1) p += __shfl_xor(p, m, 64);
    if (lane < 2) out[b * 2 + lane] = p + bcls[lane];
  }
}

extern "C" void kernel_launch(void* const* d_in, const int* in_sizes, int n_in,
                              void* d_out, int out_size, void* d_ws, size_t ws_size,
                              hipStream_t stream) {
  const int*   ids   = (const int*)d_in[0];
  const float* emb   = (const float*)d_in[1];
  const float* Win   = (const float*)d_in[2];
  const float* bin   = (const float*)d_in[3];
  const float* Wcomp = (const float*)d_in[4];
  const float* bcomp = (const float*)d_in[5];
  const float* Wcls  = (const float*)d_in[6];
  const float* bcls  = (const float*)d_in[7];
  char* wsb = (char*)d_ws;
  short* wsbf = (short*)wsb;                            // 16 MB bf16 k1->k2 rows
  const size_t WSBF_BYTES = (size_t)BB * NSUB * K1ROWS * HH * 2;  // 16 MB
  short* WcT = (short*)(wsb + WSBF_BYTES);              // 64 KB
  short* WiT = (short*)(wsb + WSBF_BYTES + 65536);      // 32 KB
  float* out = (float*)d_out;

  hipLaunchKernelGGL(k_prep, dim3(64), dim3(256), 0, stream, Win, Wcomp, WiT, WcT);
  hipLaunchKernelGGL(k_subtree, dim3(BB * NSUB), dim3(256), 0, stream,
                     ids, emb, WiT, bin, WcT, bcomp, wsbf);
  hipLaunchKernelGGL(k_tree2, dim3(BB), dim3(256), 0, stream,
                     wsbf, WcT, bcomp, Wcls, bcls, out);
}